// Round 19
// baseline (84.358 us; speedup 1.0000x reference)
//
#include <hip/hip_runtime.h>
#include <math.h>

typedef _Float16 f16;
typedef _Float16 f16x8 __attribute__((ext_vector_type(8)));
typedef _Float16 f16x4 __attribute__((ext_vector_type(4)));
typedef float f32x4 __attribute__((ext_vector_type(4)));
typedef float f32x2 __attribute__((ext_vector_type(2)));

#define LOG2E 1.44269504088896340736f
#define LN2   0.69314718055994530942f

static constexpr int Bb = 2;      // batch
static constexpr int Ls = 2048;   // seqlen
static constexpr int Dm = 2048;   // d_inner
static constexpr int Ns = 16;     // d_state
static constexpr int Rr = 128;    // dt_rank
static constexpr int Mm = Bb * Ls;   // 4096 rows (b*l)
static constexpr int NC = 128;       // scan chunks
static constexpr int LC = Ls / NC;   // 16 steps per chunk
static constexpr int SK = 8;         // split-K for GEMM1
static constexpr int KC = Dm / SK;   // 256

// fast-path check: a2[n] == -(n+1)*LOG2E  (S4D-real init)
__device__ __forceinline__ bool fast_ok16(const float* a2r) {
    bool ok = true;
#pragma unroll
    for (int n = 0; n < 16; n++)
        ok = ok && (fabsf(a2r[n] + (float)(n + 1) * LOG2E) <= 3e-5f * (float)(n + 1));
    return ok;
}

// ---------------- GEMM1: x_dbl partials (fp16), split-K; emits x16 ----------
__global__ __launch_bounds__(256) void k_gemm1(const float* __restrict__ x,
                                               const float* __restrict__ w,
                                               f16* __restrict__ P,
                                               f16* __restrict__ x16) {
    __shared__ f16 Af[64 * 40];
    __shared__ f16 Bf[160 * 40];
    const int tid = threadIdx.x;
    const int m0 = blockIdx.x * 64;
    const int sk = blockIdx.y;
    const int kbase = sk * KC;
    const int lane = tid & 63;
    const int wv = tid >> 6;
    const int col = lane & 15;
    const int kg = lane >> 4;

    f32x4 acc[10];
#pragma unroll
    for (int i = 0; i < 10; i++) acc[i] = (f32x4){0.f, 0.f, 0.f, 0.f};

    for (int ks = 0; ks < KC / 32; ks++) {
        const int kb = kbase + ks * 32;
        if (ks) __syncthreads();
#pragma unroll
        for (int j = 0; j < 2; j++) {
            int f = tid + j * 256;
            int m = f >> 3, kq = f & 7;
            float4 v = *(const float4*)(x + (size_t)(m0 + m) * Dm + kb + kq * 4);
            f16x4 h = {(f16)v.x, (f16)v.y, (f16)v.z, (f16)v.w};
            *(f16x4*)((char*)Af + m * 80 + kq * 8) = h;
            *(f16x4*)(x16 + (size_t)(m0 + m) * Dm + kb + kq * 4) = h;
        }
#pragma unroll
        for (int j = 0; j < 5; j++) {
            int f = tid + j * 256;
            int n = f >> 3, kq = f & 7;
            float4 v = *(const float4*)(w + (size_t)n * Dm + kb + kq * 4);
            f16x4 h = {(f16)v.x, (f16)v.y, (f16)v.z, (f16)v.w};
            *(f16x4*)((char*)Bf + n * 80 + kq * 8) = h;
        }
        __syncthreads();
        f16x8 a = *(const f16x8*)((char*)Af + (wv * 16 + col) * 80 + kg * 16);
#pragma unroll
        for (int nf = 0; nf < 10; nf++) {
            f16x8 b = *(const f16x8*)((char*)Bf + (nf * 16 + col) * 80 + kg * 16);
            acc[nf] = __builtin_amdgcn_mfma_f32_16x16x32_f16(a, b, acc[nf], 0, 0, 0);
        }
    }
    f16* Pb = P + (size_t)sk * Mm * 160 + (size_t)m0 * 160;
#pragma unroll
    for (int nf = 0; nf < 10; nf++)
#pragma unroll
        for (int r = 0; r < 4; r++) {
            int row = wv * 16 + kg * 4 + r;
            Pb[(size_t)row * 160 + nf * 16 + col] = (f16)acc[nf][r];
        }
}

// ------- reduce split-K (fp16 partials), pack dun/Bm/Cm; fused prep ---------
__global__ __launch_bounds__(256) void k_red1(const f16* __restrict__ P,
                                              const float* __restrict__ dtw,
                                              const float* __restrict__ alog,
                                              f16* __restrict__ dun,
                                              float* __restrict__ Bm,
                                              float* __restrict__ Cm,
                                              f16* __restrict__ dtw16,
                                              float* __restrict__ a2) {
    int e = blockIdx.x * 256 + threadIdx.x;   // < Mm*160
    if (e < Dm * Rr) dtw16[e] = (f16)dtw[e];
    if (e < Dm * Ns) {
        int d = e >> 4, n = e & 15;
        a2[n * Dm + d] = -expf(alog[e]) * LOG2E;
    }
    int m = e / 160, c = e % 160;
    float v = 0.f;
#pragma unroll
    for (int s = 0; s < SK; s++) v += (float)P[(size_t)s * Mm * 160 + e];
    if (c < 128)      dun[(size_t)m * Rr + c] = (f16)v;
    else if (c < 144) Bm[(size_t)m * 16 + (c - 128)] = v;
    else              Cm[(size_t)m * 16 + (c - 144)] = v;
}

// ---------------- GEMM2: delta16 = softplus(dun . dtw^T + b) ----------------
__global__ __launch_bounds__(256) void k_gemm2(const f16* __restrict__ dun,
                                               const f16* __restrict__ dtw16,
                                               const float* __restrict__ bias,
                                               f16* __restrict__ delta) {
    __shared__ f16 Ad[64 * 128];
    __shared__ f16 Bd[128 * 128];
    const int tid = threadIdx.x;
    const int lane = tid & 63;
    const int wv = tid >> 6;
    const int m0 = blockIdx.x * 64;
    const int n0 = blockIdx.y * 128;
    const int col = lane & 15;
    const int kg = lane >> 4;
    const int wm = wv & 1, wn = wv >> 1;

    const uint4* gA = (const uint4*)(dun + (size_t)m0 * Rr);
#pragma unroll
    for (int j = 0; j < 4; j++) {
        int slot = tid + j * 256;
        uint4 v = gA[slot];
        int off = slot * 16;
        int row = slot >> 4;
        *(uint4*)((char*)Ad + (off ^ ((row & 7) << 4))) = v;
    }
    const uint4* gB = (const uint4*)(dtw16 + (size_t)n0 * Rr);
#pragma unroll
    for (int j = 0; j < 8; j++) {
        int slot = tid + j * 256;
        uint4 v = gB[slot];
        int off = slot * 16;
        int row = slot >> 4;
        *(uint4*)((char*)Bd + (off ^ ((row & 7) << 4))) = v;
    }
    __syncthreads();

    f32x4 acc[2][4];
#pragma unroll
    for (int i = 0; i < 2; i++)
#pragma unroll
        for (int j = 0; j < 4; j++) acc[i][j] = (f32x4){0.f, 0.f, 0.f, 0.f};

#pragma unroll
    for (int ks = 0; ks < 4; ks++) {
        f16x8 a[2], b[4];
#pragma unroll
        for (int mf = 0; mf < 2; mf++) {
            int row = wm * 32 + mf * 16 + col;
            int off = (row << 8) + ks * 64 + kg * 16;
            a[mf] = *(const f16x8*)((char*)Ad + (off ^ ((row & 7) << 4)));
        }
#pragma unroll
        for (int nf = 0; nf < 4; nf++) {
            int row = wn * 64 + nf * 16 + col;
            int off = (row << 8) + ks * 64 + kg * 16;
            b[nf] = *(const f16x8*)((char*)Bd + (off ^ ((row & 7) << 4)));
        }
#pragma unroll
        for (int mf = 0; mf < 2; mf++)
#pragma unroll
            for (int nf = 0; nf < 4; nf++)
                acc[mf][nf] = __builtin_amdgcn_mfma_f32_16x16x32_f16(a[mf], b[nf], acc[mf][nf], 0, 0, 0);
    }
#pragma unroll
    for (int mf = 0; mf < 2; mf++)
#pragma unroll
        for (int nf = 0; nf < 4; nf++) {
            int gd = n0 + wn * 64 + nf * 16 + col;
            float bv = bias[gd];
#pragma unroll
            for (int r = 0; r < 4; r++) {
                int gm = m0 + wm * 32 + mf * 16 + kg * 4 + r;
                float v = acc[mf][nf][r] + bv;
                float e2 = exp2f(-fabsf(v) * LOG2E);
                float sp = fmaxf(v, 0.f) + LN2 * log2f(1.f + e2);
                delta[(size_t)gm * Dm + gd] = (f16)sp;
            }
        }
}

// block decode (scans): dblk = bid&7, c = (bid>>3)&127, b = bid>>10
// Sl/S0 layout: [b][c][n][d] fp16 ; dsum layout: [b][c][d] fp32

// packed-f32 fast-path update: s2[k] = wp_k * s2[k] + dx * bb_k,
// wp_0 = (w^1, w^2), wp_{k+1} = wp_k * (w^2, w^2)
#define UPD16V(dx)                                                            \
    {                                                                         \
        f32x2 dx2 = {(dx), (dx)};                                             \
        f32x2 w2b = {w2s, w2s};                                               \
        f32x2 p = {w1, w2s};                                                  \
        s2[0] = __builtin_elementwise_fma(p, s2[0], dx2 * bb[0]); p *= w2b;   \
        s2[1] = __builtin_elementwise_fma(p, s2[1], dx2 * bb[1]); p *= w2b;   \
        s2[2] = __builtin_elementwise_fma(p, s2[2], dx2 * bb[2]); p *= w2b;   \
        s2[3] = __builtin_elementwise_fma(p, s2[3], dx2 * bb[3]); p *= w2b;   \
        s2[4] = __builtin_elementwise_fma(p, s2[4], dx2 * bb[4]); p *= w2b;   \
        s2[5] = __builtin_elementwise_fma(p, s2[5], dx2 * bb[5]); p *= w2b;   \
        s2[6] = __builtin_elementwise_fma(p, s2[6], dx2 * bb[6]); p *= w2b;   \
        s2[7] = __builtin_elementwise_fma(p, s2[7], dx2 * bb[7]);             \
    }

#define LOADB16(base)                                                         \
    float4 b0 = *(const float4*)&(base)[0];                                   \
    float4 b1 = *(const float4*)&(base)[4];                                   \
    float4 b2 = *(const float4*)&(base)[8];                                   \
    float4 b3 = *(const float4*)&(base)[12];                                  \
    f32x2 bb[8];                                                              \
    bb[0] = (f32x2){b0.x, b0.y}; bb[1] = (f32x2){b0.z, b0.w};                 \
    bb[2] = (f32x2){b1.x, b1.y}; bb[3] = (f32x2){b1.z, b1.w};                 \
    bb[4] = (f32x2){b2.x, b2.y}; bb[5] = (f32x2){b2.z, b2.w};                 \
    bb[6] = (f32x2){b3.x, b3.y}; bb[7] = (f32x2){b3.z, b3.w};

#define LOADC16(base)                                                         \
    float4 c0 = *(const float4*)&(base)[0];                                   \
    float4 c1 = *(const float4*)&(base)[4];                                   \
    float4 c2 = *(const float4*)&(base)[8];                                   \
    float4 c3 = *(const float4*)&(base)[12];                                  \
    f32x2 cc[8];                                                              \
    cc[0] = (f32x2){c0.x, c0.y}; cc[1] = (f32x2){c0.z, c0.w};                 \
    cc[2] = (f32x2){c1.x, c1.y}; cc[3] = (f32x2){c1.z, c1.w};                 \
    cc[4] = (f32x2){c2.x, c2.y}; cc[5] = (f32x2){c2.z, c2.w};                 \
    cc[6] = (f32x2){c3.x, c3.y}; cc[7] = (f32x2){c3.z, c3.w};

// ---------------- scan phase 1: register-chunk summaries --------------------
__global__ __launch_bounds__(256, 4) void k_scan1(const f16* __restrict__ delta,
                                                  const f16* __restrict__ x16,
                                                  const float* __restrict__ Bm,
                                                  const float* __restrict__ a2g,
                                                  f16* __restrict__ Sl,
                                                  float* __restrict__ dsumO) {
    __shared__ float bcl[LC * 16];    // 1 KB (B rows, broadcast)

    const int tid = threadIdx.x;
    const int bid = blockIdx.x;
    const int dblk = bid & 7;
    const int c = (bid >> 3) & (NC - 1);
    const int b = bid >> 10;
    const int d = dblk * 256 + tid;
    const int row0 = b * Ls + c * LC;

    if (tid < LC * 4) {
        int l = tid >> 2, q = tid & 3;
        *(float4*)&bcl[l * 16 + q * 4] = *(const float4*)(Bm + (size_t)(row0 + l) * 16 + q * 4);
    }
    const f16* dp = delta + (size_t)row0 * Dm + d;
    const f16* xp = x16 + (size_t)row0 * Dm + d;

    f16 rd0[8], rx0[8], rd1[8], rx1[8];
#pragma unroll
    for (int j = 0; j < 8; j++) { rd0[j] = dp[(size_t)j * Dm]; rx0[j] = xp[(size_t)j * Dm]; }
#pragma unroll
    for (int j = 0; j < 8; j++) { rd1[j] = dp[(size_t)(8 + j) * Dm]; rx1[j] = xp[(size_t)(8 + j) * Dm]; }

    float a2r[16];
#pragma unroll
    for (int n = 0; n < 16; n++) a2r[n] = a2g[(size_t)n * Dm + d];
    const bool fastp = fast_ok16(a2r);

    f32x2 s2[8];
#pragma unroll
    for (int n = 0; n < 8; n++) s2[n] = (f32x2){0.f, 0.f};
    float dsum = 0.f;
    __syncthreads();

    if (fastp) {
#define S1F(i, dcv, xcv)                                                      \
        {                                                                     \
            float dc = (float)(dcv), xc = (float)(xcv);                       \
            float dx = dc * xc;                                               \
            dsum += dc;                                                       \
            float w1 = exp2f(dc * (-LOG2E));                                  \
            float w2s = w1 * w1;                                              \
            LOADB16(&bcl[(i) * 16])                                           \
            UPD16V(dx)                                                        \
        }
#pragma unroll
        for (int j = 0; j < 8; j++) S1F(j, rd0[j], rx0[j])
#pragma unroll
        for (int j = 0; j < 8; j++) S1F(8 + j, rd1[j], rx1[j])
#undef S1F
    } else {
        float s[16];
#pragma unroll
        for (int n = 0; n < 16; n++) s[n] = 0.f;
#define S1S(i, dcv, xcv)                                                      \
        {                                                                     \
            float dc = (float)(dcv), xc = (float)(xcv);                       \
            float dx = dc * xc;                                               \
            dsum += dc;                                                       \
            _Pragma("unroll")                                                 \
            for (int n = 0; n < 16; n++)                                      \
                s[n] = fmaf(exp2f(dc * a2r[n]), s[n], dx * bcl[(i) * 16 + n]); \
        }
#pragma unroll
        for (int j = 0; j < 8; j++) S1S(j, rd0[j], rx0[j])
#pragma unroll
        for (int j = 0; j < 8; j++) S1S(8 + j, rd1[j], rx1[j])
#undef S1S
#pragma unroll
        for (int n = 0; n < 8; n++) s2[n] = (f32x2){s[2 * n], s[2 * n + 1]};
    }

    const size_t ob = ((size_t)(b * NC + c) * 16) * Dm + d;
#pragma unroll
    for (int n = 0; n < 8; n++) {
        Sl[ob + (size_t)(2 * n) * Dm] = (f16)s2[n].x;
        Sl[ob + (size_t)(2 * n + 1) * Dm] = (f16)s2[n].y;
    }
    dsumO[(size_t)(b * NC + c) * Dm + d] = dsum;
}

// ---------------- scan phase 2: chunk combine (pipelined 16-deep) -----------
__global__ __launch_bounds__(256) void k_scan2(const float* __restrict__ dsum,
                                               const f16* __restrict__ Sl,
                                               const float* __restrict__ a2g,
                                               f16* __restrict__ S0) {
    int e = blockIdx.x * 256 + threadIdx.x;   // < Bb*16*Dm
    int d = e & (Dm - 1);
    int n = (e >> 11) & 15;
    int b = e >> 15;
    float a2r = a2g[(size_t)n * Dm + d];
    size_t baseS = ((size_t)(b * NC) * 16 + n) * Dm + d;
    size_t baseD = (size_t)(b * NC) * Dm + d;
    const size_t cs = (size_t)16 * Dm;
    float s = 0.f;

    float dsb[16];
    f16 slb[16];
#pragma unroll
    for (int j = 0; j < 16; j++) {
        dsb[j] = dsum[baseD + (size_t)j * Dm];
        slb[j] = Sl[baseS + (size_t)j * cs];
    }
    for (int cg = 0; cg < NC / 16; cg++) {
        // prefetch next batch while computing current (addresses independent)
        float dsn[16];
        f16 sln[16];
        const int nb = (cg + 1 < NC / 16) ? (cg + 1) * 16 : cg * 16;
#pragma unroll
        for (int j = 0; j < 16; j++) {
            dsn[j] = dsum[baseD + (size_t)(nb + j) * Dm];
            sln[j] = Sl[baseS + (size_t)(nb + j) * cs];
        }
#pragma unroll
        for (int j = 0; j < 16; j++) {
            S0[baseS + (size_t)(cg * 16 + j) * cs] = (f16)s;
            s = fmaf(exp2f(dsb[j] * a2r), s, (float)slb[j]);
        }
#pragma unroll
        for (int j = 0; j < 16; j++) { dsb[j] = dsn[j]; slb[j] = sln[j]; }
    }
}

// ---------------- scan phase 3: register-chunk rescan, emit y ---------------
__global__ __launch_bounds__(256, 4) void k_scan3(const f16* __restrict__ delta,
                                                  const f16* __restrict__ x16,
                                                  const float* __restrict__ Bm,
                                                  const float* __restrict__ Cm,
                                                  const float* __restrict__ a2g,
                                                  const f16* __restrict__ S0,
                                                  const float* __restrict__ Dpar,
                                                  float* __restrict__ out) {
    __shared__ float bcl[LC * 32];    // 2 KB (B row | C row, broadcast)

    const int tid = threadIdx.x;
    const int bid = blockIdx.x;
    const int dblk = bid & 7;
    const int c = (bid >> 3) & (NC - 1);
    const int b = bid >> 10;
    const int d = dblk * 256 + tid;
    const int row0 = b * Ls + c * LC;

    if (tid < LC * 4) {
        int l = tid >> 2, q = tid & 3;
        *(float4*)&bcl[l * 32 + q * 4] = *(const float4*)(Bm + (size_t)(row0 + l) * 16 + q * 4);
    } else if (tid < LC * 8) {
        int t = tid - LC * 4;
        int l = t >> 2, q = t & 3;
        *(float4*)&bcl[l * 32 + 16 + q * 4] = *(const float4*)(Cm + (size_t)(row0 + l) * 16 + q * 4);
    }
    const f16* dp = delta + (size_t)row0 * Dm + d;
    const f16* xp = x16 + (size_t)row0 * Dm + d;

    f16 rd0[8], rx0[8], rd1[8], rx1[8];
#pragma unroll
    for (int j = 0; j < 8; j++) { rd0[j] = dp[(size_t)j * Dm]; rx0[j] = xp[(size_t)j * Dm]; }
#pragma unroll
    for (int j = 0; j < 8; j++) { rd1[j] = dp[(size_t)(8 + j) * Dm]; rx1[j] = xp[(size_t)(8 + j) * Dm]; }

    float a2r[16];
#pragma unroll
    for (int n = 0; n < 16; n++) a2r[n] = a2g[(size_t)n * Dm + d];
    const bool fastp = fast_ok16(a2r);

    const size_t ob = ((size_t)(b * NC + c) * 16) * Dm + d;
    f32x2 s2[8];
#pragma unroll
    for (int n = 0; n < 8; n++) {
        s2[n].x = (float)S0[ob + (size_t)(2 * n) * Dm];
        s2[n].y = (float)S0[ob + (size_t)(2 * n + 1) * Dm];
    }
    const float Dp = Dpar[d];
    float* optr = out + (size_t)row0 * Dm + d;
    __syncthreads();

    if (fastp) {
#define S3F(i, dcv, xcv)                                                      \
        {                                                                     \
            float dc = (float)(dcv), xc = (float)(xcv);                       \
            float dx = dc * xc;                                               \
            float w1 = exp2f(dc * (-LOG2E));                                  \
            float w2s = w1 * w1;                                              \
            LOADB16(&bcl[(i) * 32])                                           \
            LOADC16(&bcl[(i) * 32 + 16])                                      \
            UPD16V(dx)                                                        \
            f32x2 ya = s2[0] * cc[0];                                         \
            f32x2 yb = s2[1] * cc[1];                                         \
            ya = __builtin_elementwise_fma(s2[2], cc[2], ya);                 \
            yb = __builtin_elementwise_fma(s2[3], cc[3], yb);                 \
            ya = __builtin_elementwise_fma(s2[4], cc[4], ya);                 \
            yb = __builtin_elementwise_fma(s2[5], cc[5], yb);                 \
            ya = __builtin_elementwise_fma(s2[6], cc[6], ya);                 \
            yb = __builtin_elementwise_fma(s2[7], cc[7], yb);                 \
            float yv = (ya.x + ya.y) + (yb.x + yb.y);                         \
            optr[(size_t)(i) * Dm] = fmaf(xc, Dp, yv);                        \
        }
#pragma unroll
        for (int j = 0; j < 8; j++) S3F(j, rd0[j], rx0[j])
#pragma unroll
        for (int j = 0; j < 8; j++) S3F(8 + j, rd1[j], rx1[j])
#undef S3F
    } else {
        float s[16];
#pragma unroll
        for (int n = 0; n < 8; n++) { s[2 * n] = s2[n].x; s[2 * n + 1] = s2[n].y; }
#define S3S(i, dcv, xcv)                                                      \
        {                                                                     \
            float dc = (float)(dcv), xc = (float)(xcv);                       \
            float dx = dc * xc;                                               \
            float yv = 0.f;                                                   \
            _Pragma("unroll")                                                 \
            for (int n = 0; n < 16; n++) {                                    \
                s[n] = fmaf(exp2f(dc * a2r[n]), s[n], dx * bcl[(i) * 32 + n]); \
                yv = fmaf(s[n], bcl[(i) * 32 + 16 + n], yv);                  \
            }                                                                 \
            optr[(size_t)(i) * Dm] = fmaf(xc, Dp, yv);                        \
        }
#pragma unroll
        for (int j = 0; j < 8; j++) S3S(j, rd0[j], rx0[j])
#pragma unroll
        for (int j = 0; j < 8; j++) S3S(8 + j, rd1[j], rx1[j])
#undef S3S
    }
}

// ---------------- host launcher ---------------------------------------------
extern "C" void kernel_launch(void* const* d_in, const int* in_sizes, int n_in,
                              void* d_out, int out_size, void* d_ws, size_t ws_size,
                              hipStream_t stream) {
    const float* x    = (const float*)d_in[0];
    const float* xw   = (const float*)d_in[1];
    const float* dtw  = (const float*)d_in[2];
    const float* dtb  = (const float*)d_in[3];
    const float* alog = (const float*)d_in[4];
    const float* dpar = (const float*)d_in[5];
    float* out = (float*)d_out;

    char* ws = (char*)d_ws;
    size_t off = 0;
    auto alloc = [&](size_t bytes) {
        char* p = ws + off;
        off += (bytes + 255) & ~(size_t)255;
        return p;
    };
    f16*   dun    = (f16*)  alloc((size_t)Mm * Rr * 2);             // 1 MB
    float* BmA    = (float*)alloc((size_t)Mm * 16 * 4);             // 256 KB
    float* CmA    = (float*)alloc((size_t)Mm * 16 * 4);             // 256 KB
    f16*   Pp     = (f16*)  alloc((size_t)SK * Mm * 160 * 2);       // 10.5 MB
    f16*   deltaA = (f16*)  alloc((size_t)Mm * Dm * 2);             // 16.8 MB
    f16*   x16A   = (f16*)  alloc((size_t)Mm * Dm * 2);             // 16.8 MB
    f16*   SlA    = (f16*)  alloc((size_t)Bb * NC * 16 * Dm * 2);   // 16.8 MB
    f16*   S0A    = (f16*)  alloc((size_t)Bb * NC * 16 * Dm * 2);   // 16.8 MB
    float* dsumA  = (float*)alloc((size_t)Bb * NC * Dm * 4);        // 2 MB
    f16*   dtw16  = (f16*)  alloc((size_t)Dm * Rr * 2);             // 512 KB
    float* a2A    = (float*)alloc((size_t)Ns * Dm * 4);             // 128 KB

    hipLaunchKernelGGL(k_gemm1, dim3(Mm / 64, SK), dim3(256), 0, stream,
                       x, xw, Pp, x16A);
    hipLaunchKernelGGL(k_red1, dim3((Mm * 160) / 256), dim3(256), 0, stream,
                       Pp, dtw, alog, dun, BmA, CmA, dtw16, a2A);
    hipLaunchKernelGGL(k_gemm2, dim3(Mm / 64, Dm / 128), dim3(256), 0, stream,
                       dun, dtw16, dtb, deltaA);
    hipLaunchKernelGGL(k_scan1, dim3(Bb * 8 * NC), dim3(256), 0, stream,
                       deltaA, x16A, BmA, a2A, SlA, dsumA);
    hipLaunchKernelGGL(k_scan2, dim3((Bb * 16 * Dm) / 256), dim3(256), 0, stream,
                       dsumA, SlA, a2A, S0A);
    hipLaunchKernelGGL(k_scan3, dim3(Bb * 8 * NC), dim3(256), 0, stream,
                       deltaA, x16A, BmA, CmA, a2A, S0A, dpar, out);
}

// Round 20
// 83.155 us; speedup vs baseline: 1.0145x; 1.0145x over previous
//
#include <hip/hip_runtime.h>
#include <math.h>

typedef _Float16 f16;
typedef _Float16 f16x8 __attribute__((ext_vector_type(8)));
typedef _Float16 f16x4 __attribute__((ext_vector_type(4)));
typedef float f32x4 __attribute__((ext_vector_type(4)));
typedef float f32x2 __attribute__((ext_vector_type(2)));

#define LOG2E 1.44269504088896340736f
#define LN2   0.69314718055994530942f

static constexpr int Bb = 2;      // batch
static constexpr int Ls = 2048;   // seqlen
static constexpr int Dm = 2048;   // d_inner
static constexpr int Ns = 16;     // d_state
static constexpr int Rr = 128;    // dt_rank
static constexpr int Mm = Bb * Ls;   // 4096 rows (b*l)
static constexpr int NC = 128;       // scan chunks
static constexpr int LC = Ls / NC;   // 16 steps per chunk
static constexpr int SK = 8;         // split-K for GEMM1
static constexpr int KC = Dm / SK;   // 256

// fast-path check: a2[n] == -(n+1)*LOG2E  (S4D-real init)
__device__ __forceinline__ bool fast_ok16(const float* a2r) {
    bool ok = true;
#pragma unroll
    for (int n = 0; n < 16; n++)
        ok = ok && (fabsf(a2r[n] + (float)(n + 1) * LOG2E) <= 3e-5f * (float)(n + 1));
    return ok;
}

// ---------------- GEMM1: x_dbl partials (fp16), split-K; emits x16 ----------
__global__ __launch_bounds__(256) void k_gemm1(const float* __restrict__ x,
                                               const float* __restrict__ w,
                                               f16* __restrict__ P,
                                               f16* __restrict__ x16) {
    __shared__ f16 Af[64 * 40];
    __shared__ f16 Bf[160 * 40];
    const int tid = threadIdx.x;
    const int m0 = blockIdx.x * 64;
    const int sk = blockIdx.y;
    const int kbase = sk * KC;
    const int lane = tid & 63;
    const int wv = tid >> 6;
    const int col = lane & 15;
    const int kg = lane >> 4;

    f32x4 acc[10];
#pragma unroll
    for (int i = 0; i < 10; i++) acc[i] = (f32x4){0.f, 0.f, 0.f, 0.f};

    for (int ks = 0; ks < KC / 32; ks++) {
        const int kb = kbase + ks * 32;
        if (ks) __syncthreads();
#pragma unroll
        for (int j = 0; j < 2; j++) {
            int f = tid + j * 256;
            int m = f >> 3, kq = f & 7;
            float4 v = *(const float4*)(x + (size_t)(m0 + m) * Dm + kb + kq * 4);
            f16x4 h = {(f16)v.x, (f16)v.y, (f16)v.z, (f16)v.w};
            *(f16x4*)((char*)Af + m * 80 + kq * 8) = h;
            *(f16x4*)(x16 + (size_t)(m0 + m) * Dm + kb + kq * 4) = h;
        }
#pragma unroll
        for (int j = 0; j < 5; j++) {
            int f = tid + j * 256;
            int n = f >> 3, kq = f & 7;
            float4 v = *(const float4*)(w + (size_t)n * Dm + kb + kq * 4);
            f16x4 h = {(f16)v.x, (f16)v.y, (f16)v.z, (f16)v.w};
            *(f16x4*)((char*)Bf + n * 80 + kq * 8) = h;
        }
        __syncthreads();
        f16x8 a = *(const f16x8*)((char*)Af + (wv * 16 + col) * 80 + kg * 16);
#pragma unroll
        for (int nf = 0; nf < 10; nf++) {
            f16x8 b = *(const f16x8*)((char*)Bf + (nf * 16 + col) * 80 + kg * 16);
            acc[nf] = __builtin_amdgcn_mfma_f32_16x16x32_f16(a, b, acc[nf], 0, 0, 0);
        }
    }
    f16* Pb = P + (size_t)sk * Mm * 160 + (size_t)m0 * 160;
#pragma unroll
    for (int nf = 0; nf < 10; nf++)
#pragma unroll
        for (int r = 0; r < 4; r++) {
            int row = wv * 16 + kg * 4 + r;
            Pb[(size_t)row * 160 + nf * 16 + col] = (f16)acc[nf][r];
        }
}

// ------- reduce split-K (fp16 partials), pack dun/Bm/Cm; fused prep ---------
__global__ __launch_bounds__(256) void k_red1(const f16* __restrict__ P,
                                              const float* __restrict__ dtw,
                                              const float* __restrict__ alog,
                                              f16* __restrict__ dun,
                                              float* __restrict__ Bm,
                                              float* __restrict__ Cm,
                                              f16* __restrict__ dtw16,
                                              float* __restrict__ a2) {
    int e = blockIdx.x * 256 + threadIdx.x;   // < Mm*160
    if (e < Dm * Rr) dtw16[e] = (f16)dtw[e];
    if (e < Dm * Ns) {
        int d = e >> 4, n = e & 15;
        a2[n * Dm + d] = -expf(alog[e]) * LOG2E;
    }
    int m = e / 160, c = e % 160;
    float v = 0.f;
#pragma unroll
    for (int s = 0; s < SK; s++) v += (float)P[(size_t)s * Mm * 160 + e];
    if (c < 128)      dun[(size_t)m * Rr + c] = (f16)v;
    else if (c < 144) Bm[(size_t)m * 16 + (c - 128)] = v;
    else              Cm[(size_t)m * 16 + (c - 144)] = v;
}

// ---------------- GEMM2: delta16 = softplus(dun . dtw^T + b) ----------------
__global__ __launch_bounds__(256) void k_gemm2(const f16* __restrict__ dun,
                                               const f16* __restrict__ dtw16,
                                               const float* __restrict__ bias,
                                               f16* __restrict__ delta) {
    __shared__ f16 Ad[64 * 128];
    __shared__ f16 Bd[128 * 128];
    const int tid = threadIdx.x;
    const int lane = tid & 63;
    const int wv = tid >> 6;
    const int m0 = blockIdx.x * 64;
    const int n0 = blockIdx.y * 128;
    const int col = lane & 15;
    const int kg = lane >> 4;
    const int wm = wv & 1, wn = wv >> 1;

    const uint4* gA = (const uint4*)(dun + (size_t)m0 * Rr);
#pragma unroll
    for (int j = 0; j < 4; j++) {
        int slot = tid + j * 256;
        uint4 v = gA[slot];
        int off = slot * 16;
        int row = slot >> 4;
        *(uint4*)((char*)Ad + (off ^ ((row & 7) << 4))) = v;
    }
    const uint4* gB = (const uint4*)(dtw16 + (size_t)n0 * Rr);
#pragma unroll
    for (int j = 0; j < 8; j++) {
        int slot = tid + j * 256;
        uint4 v = gB[slot];
        int off = slot * 16;
        int row = slot >> 4;
        *(uint4*)((char*)Bd + (off ^ ((row & 7) << 4))) = v;
    }
    __syncthreads();

    f32x4 acc[2][4];
#pragma unroll
    for (int i = 0; i < 2; i++)
#pragma unroll
        for (int j = 0; j < 4; j++) acc[i][j] = (f32x4){0.f, 0.f, 0.f, 0.f};

#pragma unroll
    for (int ks = 0; ks < 4; ks++) {
        f16x8 a[2], b[4];
#pragma unroll
        for (int mf = 0; mf < 2; mf++) {
            int row = wm * 32 + mf * 16 + col;
            int off = (row << 8) + ks * 64 + kg * 16;
            a[mf] = *(const f16x8*)((char*)Ad + (off ^ ((row & 7) << 4)));
        }
#pragma unroll
        for (int nf = 0; nf < 4; nf++) {
            int row = wn * 64 + nf * 16 + col;
            int off = (row << 8) + ks * 64 + kg * 16;
            b[nf] = *(const f16x8*)((char*)Bd + (off ^ ((row & 7) << 4)));
        }
#pragma unroll
        for (int mf = 0; mf < 2; mf++)
#pragma unroll
            for (int nf = 0; nf < 4; nf++)
                acc[mf][nf] = __builtin_amdgcn_mfma_f32_16x16x32_f16(a[mf], b[nf], acc[mf][nf], 0, 0, 0);
    }
#pragma unroll
    for (int mf = 0; mf < 2; mf++)
#pragma unroll
        for (int nf = 0; nf < 4; nf++) {
            int gd = n0 + wn * 64 + nf * 16 + col;
            float bv = bias[gd];
#pragma unroll
            for (int r = 0; r < 4; r++) {
                int gm = m0 + wm * 32 + mf * 16 + kg * 4 + r;
                float v = acc[mf][nf][r] + bv;
                float e2 = exp2f(-fabsf(v) * LOG2E);
                float sp = fmaxf(v, 0.f) + LN2 * log2f(1.f + e2);
                delta[(size_t)gm * Dm + gd] = (f16)sp;
            }
        }
}

// block decode (scans): dblk = bid&7, c = (bid>>3)&127, b = bid>>10
// Sl/S0 layout: [b][c][n][d] fp16 ; dsum layout: [b][c][d] fp32

// packed-f32 fast-path update: s2[k] = wp_k * s2[k] + dx * bb_k,
// wp_0 = (w^1, w^2), wp_{k+1} = wp_k * (w^2, w^2)
#define UPD16V(dx)                                                            \
    {                                                                         \
        f32x2 dx2 = {(dx), (dx)};                                             \
        f32x2 w2b = {w2s, w2s};                                               \
        f32x2 p = {w1, w2s};                                                  \
        s2[0] = __builtin_elementwise_fma(p, s2[0], dx2 * bb[0]); p *= w2b;   \
        s2[1] = __builtin_elementwise_fma(p, s2[1], dx2 * bb[1]); p *= w2b;   \
        s2[2] = __builtin_elementwise_fma(p, s2[2], dx2 * bb[2]); p *= w2b;   \
        s2[3] = __builtin_elementwise_fma(p, s2[3], dx2 * bb[3]); p *= w2b;   \
        s2[4] = __builtin_elementwise_fma(p, s2[4], dx2 * bb[4]); p *= w2b;   \
        s2[5] = __builtin_elementwise_fma(p, s2[5], dx2 * bb[5]); p *= w2b;   \
        s2[6] = __builtin_elementwise_fma(p, s2[6], dx2 * bb[6]); p *= w2b;   \
        s2[7] = __builtin_elementwise_fma(p, s2[7], dx2 * bb[7]);             \
    }

#define LOADB16(base)                                                         \
    float4 b0 = *(const float4*)&(base)[0];                                   \
    float4 b1 = *(const float4*)&(base)[4];                                   \
    float4 b2 = *(const float4*)&(base)[8];                                   \
    float4 b3 = *(const float4*)&(base)[12];                                  \
    f32x2 bb[8];                                                              \
    bb[0] = (f32x2){b0.x, b0.y}; bb[1] = (f32x2){b0.z, b0.w};                 \
    bb[2] = (f32x2){b1.x, b1.y}; bb[3] = (f32x2){b1.z, b1.w};                 \
    bb[4] = (f32x2){b2.x, b2.y}; bb[5] = (f32x2){b2.z, b2.w};                 \
    bb[6] = (f32x2){b3.x, b3.y}; bb[7] = (f32x2){b3.z, b3.w};

#define LOADC16(base)                                                         \
    float4 c0 = *(const float4*)&(base)[0];                                   \
    float4 c1 = *(const float4*)&(base)[4];                                   \
    float4 c2 = *(const float4*)&(base)[8];                                   \
    float4 c3 = *(const float4*)&(base)[12];                                  \
    f32x2 cc[8];                                                              \
    cc[0] = (f32x2){c0.x, c0.y}; cc[1] = (f32x2){c0.z, c0.w};                 \
    cc[2] = (f32x2){c1.x, c1.y}; cc[3] = (f32x2){c1.z, c1.w};                 \
    cc[4] = (f32x2){c2.x, c2.y}; cc[5] = (f32x2){c2.z, c2.w};                 \
    cc[6] = (f32x2){c3.x, c3.y}; cc[7] = (f32x2){c3.z, c3.w};

// ---------------- scan phase 1: register-chunk summaries --------------------
__global__ __launch_bounds__(256, 4) void k_scan1(const f16* __restrict__ delta,
                                                  const f16* __restrict__ x16,
                                                  const float* __restrict__ Bm,
                                                  const float* __restrict__ a2g,
                                                  f16* __restrict__ Sl,
                                                  float* __restrict__ dsumO) {
    __shared__ float bcl[LC * 16];    // 1 KB (B rows, broadcast)

    const int tid = threadIdx.x;
    const int bid = blockIdx.x;
    const int dblk = bid & 7;
    const int c = (bid >> 3) & (NC - 1);
    const int b = bid >> 10;
    const int d = dblk * 256 + tid;
    const int row0 = b * Ls + c * LC;

    if (tid < LC * 4) {
        int l = tid >> 2, q = tid & 3;
        *(float4*)&bcl[l * 16 + q * 4] = *(const float4*)(Bm + (size_t)(row0 + l) * 16 + q * 4);
    }
    const f16* dp = delta + (size_t)row0 * Dm + d;
    const f16* xp = x16 + (size_t)row0 * Dm + d;

    f16 rd0[8], rx0[8], rd1[8], rx1[8];
#pragma unroll
    for (int j = 0; j < 8; j++) { rd0[j] = dp[(size_t)j * Dm]; rx0[j] = xp[(size_t)j * Dm]; }
#pragma unroll
    for (int j = 0; j < 8; j++) { rd1[j] = dp[(size_t)(8 + j) * Dm]; rx1[j] = xp[(size_t)(8 + j) * Dm]; }

    float a2r[16];
#pragma unroll
    for (int n = 0; n < 16; n++) a2r[n] = a2g[(size_t)n * Dm + d];
    const bool fastp = fast_ok16(a2r);

    f32x2 s2[8];
#pragma unroll
    for (int n = 0; n < 8; n++) s2[n] = (f32x2){0.f, 0.f};
    float dsum = 0.f;
    __syncthreads();

    if (fastp) {
#define S1F(i, dcv, xcv)                                                      \
        {                                                                     \
            float dc = (float)(dcv), xc = (float)(xcv);                       \
            float dx = dc * xc;                                               \
            dsum += dc;                                                       \
            float w1 = exp2f(dc * (-LOG2E));                                  \
            float w2s = w1 * w1;                                              \
            LOADB16(&bcl[(i) * 16])                                           \
            UPD16V(dx)                                                        \
        }
#pragma unroll
        for (int j = 0; j < 8; j++) S1F(j, rd0[j], rx0[j])
#pragma unroll
        for (int j = 0; j < 8; j++) S1F(8 + j, rd1[j], rx1[j])
#undef S1F
    } else {
        float s[16];
#pragma unroll
        for (int n = 0; n < 16; n++) s[n] = 0.f;
#define S1S(i, dcv, xcv)                                                      \
        {                                                                     \
            float dc = (float)(dcv), xc = (float)(xcv);                       \
            float dx = dc * xc;                                               \
            dsum += dc;                                                       \
            _Pragma("unroll")                                                 \
            for (int n = 0; n < 16; n++)                                      \
                s[n] = fmaf(exp2f(dc * a2r[n]), s[n], dx * bcl[(i) * 16 + n]); \
        }
#pragma unroll
        for (int j = 0; j < 8; j++) S1S(j, rd0[j], rx0[j])
#pragma unroll
        for (int j = 0; j < 8; j++) S1S(8 + j, rd1[j], rx1[j])
#undef S1S
#pragma unroll
        for (int n = 0; n < 8; n++) s2[n] = (f32x2){s[2 * n], s[2 * n + 1]};
    }

    const size_t ob = ((size_t)(b * NC + c) * 16) * Dm + d;
#pragma unroll
    for (int n = 0; n < 8; n++) {
        Sl[ob + (size_t)(2 * n) * Dm] = (f16)s2[n].x;
        Sl[ob + (size_t)(2 * n + 1) * Dm] = (f16)s2[n].y;
    }
    dsumO[(size_t)(b * NC + c) * Dm + d] = dsum;
}

// ---------------- scan phase 2: chunk combine (16-deep batches) -------------
__global__ __launch_bounds__(256) void k_scan2(const float* __restrict__ dsum,
                                               const f16* __restrict__ Sl,
                                               const float* __restrict__ a2g,
                                               f16* __restrict__ S0) {
    int e = blockIdx.x * 256 + threadIdx.x;   // < Bb*16*Dm
    int d = e & (Dm - 1);
    int n = (e >> 11) & 15;
    int b = e >> 15;
    float a2r = a2g[(size_t)n * Dm + d];
    size_t baseS = ((size_t)(b * NC) * 16 + n) * Dm + d;
    size_t baseD = (size_t)(b * NC) * Dm + d;
    const size_t cs = (size_t)16 * Dm;
    float s = 0.f;
    for (int cg = 0; cg < NC / 16; cg++) {
        float dsb[16];
        f16 slb[16];
#pragma unroll
        for (int j = 0; j < 16; j++) {
            dsb[j] = dsum[baseD + (size_t)(cg * 16 + j) * Dm];
            slb[j] = Sl[baseS + (size_t)(cg * 16 + j) * cs];
        }
#pragma unroll
        for (int j = 0; j < 16; j++) {
            S0[baseS + (size_t)(cg * 16 + j) * cs] = (f16)s;
            s = fmaf(exp2f(dsb[j] * a2r), s, (float)slb[j]);
        }
    }
}

// ---------------- scan phase 3: register-chunk rescan, emit y ---------------
__global__ __launch_bounds__(256, 4) void k_scan3(const f16* __restrict__ delta,
                                                  const f16* __restrict__ x16,
                                                  const float* __restrict__ Bm,
                                                  const float* __restrict__ Cm,
                                                  const float* __restrict__ a2g,
                                                  const f16* __restrict__ S0,
                                                  const float* __restrict__ Dpar,
                                                  float* __restrict__ out) {
    __shared__ float bcl[LC * 32];    // 2 KB (B row | C row, broadcast)

    const int tid = threadIdx.x;
    const int bid = blockIdx.x;
    const int dblk = bid & 7;
    const int c = (bid >> 3) & (NC - 1);
    const int b = bid >> 10;
    const int d = dblk * 256 + tid;
    const int row0 = b * Ls + c * LC;

    if (tid < LC * 4) {
        int l = tid >> 2, q = tid & 3;
        *(float4*)&bcl[l * 32 + q * 4] = *(const float4*)(Bm + (size_t)(row0 + l) * 16 + q * 4);
    } else if (tid < LC * 8) {
        int t = tid - LC * 4;
        int l = t >> 2, q = t & 3;
        *(float4*)&bcl[l * 32 + 16 + q * 4] = *(const float4*)(Cm + (size_t)(row0 + l) * 16 + q * 4);
    }
    const f16* dp = delta + (size_t)row0 * Dm + d;
    const f16* xp = x16 + (size_t)row0 * Dm + d;

    f16 rd0[8], rx0[8], rd1[8], rx1[8];
#pragma unroll
    for (int j = 0; j < 8; j++) { rd0[j] = dp[(size_t)j * Dm]; rx0[j] = xp[(size_t)j * Dm]; }
#pragma unroll
    for (int j = 0; j < 8; j++) { rd1[j] = dp[(size_t)(8 + j) * Dm]; rx1[j] = xp[(size_t)(8 + j) * Dm]; }

    float a2r[16];
#pragma unroll
    for (int n = 0; n < 16; n++) a2r[n] = a2g[(size_t)n * Dm + d];
    const bool fastp = fast_ok16(a2r);

    const size_t ob = ((size_t)(b * NC + c) * 16) * Dm + d;
    f32x2 s2[8];
#pragma unroll
    for (int n = 0; n < 8; n++) {
        s2[n].x = (float)S0[ob + (size_t)(2 * n) * Dm];
        s2[n].y = (float)S0[ob + (size_t)(2 * n + 1) * Dm];
    }
    const float Dp = Dpar[d];
    float* optr = out + (size_t)row0 * Dm + d;
    __syncthreads();

    if (fastp) {
#define S3F(i, dcv, xcv)                                                      \
        {                                                                     \
            float dc = (float)(dcv), xc = (float)(xcv);                       \
            float dx = dc * xc;                                               \
            float w1 = exp2f(dc * (-LOG2E));                                  \
            float w2s = w1 * w1;                                              \
            LOADB16(&bcl[(i) * 32])                                           \
            LOADC16(&bcl[(i) * 32 + 16])                                      \
            UPD16V(dx)                                                        \
            f32x2 ya = s2[0] * cc[0];                                         \
            f32x2 yb = s2[1] * cc[1];                                         \
            ya = __builtin_elementwise_fma(s2[2], cc[2], ya);                 \
            yb = __builtin_elementwise_fma(s2[3], cc[3], yb);                 \
            ya = __builtin_elementwise_fma(s2[4], cc[4], ya);                 \
            yb = __builtin_elementwise_fma(s2[5], cc[5], yb);                 \
            ya = __builtin_elementwise_fma(s2[6], cc[6], ya);                 \
            yb = __builtin_elementwise_fma(s2[7], cc[7], yb);                 \
            float yv = (ya.x + ya.y) + (yb.x + yb.y);                         \
            optr[(size_t)(i) * Dm] = fmaf(xc, Dp, yv);                        \
        }
#pragma unroll
        for (int j = 0; j < 8; j++) S3F(j, rd0[j], rx0[j])
#pragma unroll
        for (int j = 0; j < 8; j++) S3F(8 + j, rd1[j], rx1[j])
#undef S3F
    } else {
        float s[16];
#pragma unroll
        for (int n = 0; n < 8; n++) { s[2 * n] = s2[n].x; s[2 * n + 1] = s2[n].y; }
#define S3S(i, dcv, xcv)                                                      \
        {                                                                     \
            float dc = (float)(dcv), xc = (float)(xcv);                       \
            float dx = dc * xc;                                               \
            float yv = 0.f;                                                   \
            _Pragma("unroll")                                                 \
            for (int n = 0; n < 16; n++) {                                    \
                s[n] = fmaf(exp2f(dc * a2r[n]), s[n], dx * bcl[(i) * 32 + n]); \
                yv = fmaf(s[n], bcl[(i) * 32 + 16 + n], yv);                  \
            }                                                                 \
            optr[(size_t)(i) * Dm] = fmaf(xc, Dp, yv);                        \
        }
#pragma unroll
        for (int j = 0; j < 8; j++) S3S(j, rd0[j], rx0[j])
#pragma unroll
        for (int j = 0; j < 8; j++) S3S(8 + j, rd1[j], rx1[j])
#undef S3S
    }
}

// ---------------- host launcher ---------------------------------------------
extern "C" void kernel_launch(void* const* d_in, const int* in_sizes, int n_in,
                              void* d_out, int out_size, void* d_ws, size_t ws_size,
                              hipStream_t stream) {
    const float* x    = (const float*)d_in[0];
    const float* xw   = (const float*)d_in[1];
    const float* dtw  = (const float*)d_in[2];
    const float* dtb  = (const float*)d_in[3];
    const float* alog = (const float*)d_in[4];
    const float* dpar = (const float*)d_in[5];
    float* out = (float*)d_out;

    char* ws = (char*)d_ws;
    size_t off = 0;
    auto alloc = [&](size_t bytes) {
        char* p = ws + off;
        off += (bytes + 255) & ~(size_t)255;
        return p;
    };
    f16*   dun    = (f16*)  alloc((size_t)Mm * Rr * 2);             // 1 MB
    float* BmA    = (float*)alloc((size_t)Mm * 16 * 4);             // 256 KB
    float* CmA    = (float*)alloc((size_t)Mm * 16 * 4);             // 256 KB
    f16*   Pp     = (f16*)  alloc((size_t)SK * Mm * 160 * 2);       // 10.5 MB
    f16*   deltaA = (f16*)  alloc((size_t)Mm * Dm * 2);             // 16.8 MB
    f16*   x16A   = (f16*)  alloc((size_t)Mm * Dm * 2);             // 16.8 MB
    f16*   SlA    = (f16*)  alloc((size_t)Bb * NC * 16 * Dm * 2);   // 16.8 MB
    f16*   S0A    = (f16*)  alloc((size_t)Bb * NC * 16 * Dm * 2);   // 16.8 MB
    float* dsumA  = (float*)alloc((size_t)Bb * NC * Dm * 4);        // 2 MB
    f16*   dtw16  = (f16*)  alloc((size_t)Dm * Rr * 2);             // 512 KB
    float* a2A    = (float*)alloc((size_t)Ns * Dm * 4);             // 128 KB

    hipLaunchKernelGGL(k_gemm1, dim3(Mm / 64, SK), dim3(256), 0, stream,
                       x, xw, Pp, x16A);
    hipLaunchKernelGGL(k_red1, dim3((Mm * 160) / 256), dim3(256), 0, stream,
                       Pp, dtw, alog, dun, BmA, CmA, dtw16, a2A);
    hipLaunchKernelGGL(k_gemm2, dim3(Mm / 64, Dm / 128), dim3(256), 0, stream,
                       dun, dtw16, dtb, deltaA);
    hipLaunchKernelGGL(k_scan1, dim3(Bb * 8 * NC), dim3(256), 0, stream,
                       deltaA, x16A, BmA, a2A, SlA, dsumA);
    hipLaunchKernelGGL(k_scan2, dim3((Bb * 16 * Dm) / 256), dim3(256), 0, stream,
                       dsumA, SlA, a2A, S0A);
    hipLaunchKernelGGL(k_scan3, dim3(Bb * 8 * NC), dim3(256), 0, stream,
                       deltaA, x16A, BmA, CmA, a2A, S0A, dpar, out);
}